// Round 5
// baseline (22.207 us; speedup 1.0000x reference)
//
#include <hip/hip_runtime.h>
#include <math.h>

// Problem constants: B=4, R=4096, S=48, C=32
#define NRAYS   (4 * 4096)   // 16384
#define S_SAMP  48
#define C_CH    32
#define SM1     (S_SAMP - 1) // 47 midpoints

// Output flat layout (floats):
#define OFF_RGB   0
#define OFF_DEP   (NRAYS * C_CH)
#define OFF_W     (OFF_DEP + NRAYS)
#define OFF_WT    (OFF_W + NRAYS * SM1)

__device__ __forceinline__ float alpha_of(float da, float db, float za, float zb) {
    const float dmid = 0.5f * (da + db) - 1.0f;
    // fast stable softplus: max(x,0) + log(1 + exp(-|x|))
    const float e  = __expf(-fabsf(dmid));
    const float sp = fmaxf(dmid, 0.0f) + __logf(1.0f + e);
    return 1.0f - __expf(-sp * (zb - za));
}

// One 32-lane group per ray (2 rays per wave), one float channel per lane.
// Phase 1: lane l owns midpoints 2l, 2l+1 (lanes 24..31 own none); alphas
//   computed independently; exclusive transmittance via 5-step shfl_up
//   prefix product over the 32-lane group.
// Phase 2: lane l owns channel l; per-midpoint weight broadcast from its
//   owner lane via compile-time-indexed shfl.
__global__ __launch_bounds__(256) void fused3_kernel(
    const float* __restrict__ colors,     // [NRAYS, S, C]
    const float* __restrict__ densities,  // [NRAYS, S]
    const float* __restrict__ depths,     // [NRAYS, S]
    float* __restrict__ out)
{
    const int tid = blockIdx.x * 256 + threadIdx.x;
    const int ray = tid >> 5;
    const int l   = tid & 31;

    const float* __restrict__ den = densities + (size_t)ray * S_SAMP;
    const float* __restrict__ dep = depths    + (size_t)ray * S_SAMP;

    // ---- Phase 1: weights via lane-parallel scan -------------------------
    const int m0 = 2 * l;                 // first midpoint owned by this lane
    float d0 = 0.f, d1 = 0.f, d2 = 0.f, z0 = 0.f, z1 = 0.f, z2 = 0.f;
    if (l < 24) {                         // owns midpoint m0 (and m0+1 if l<23)
        d0 = den[m0];     z0 = dep[m0];
        d1 = den[m0 + 1]; z1 = dep[m0 + 1];
        if (l < 23) { d2 = den[m0 + 2]; z2 = dep[m0 + 2]; }
    }

    const float a0 = (l < 24) ? alpha_of(d0, d1, z0, z1) : 0.0f;
    const float a1 = (l < 23) ? alpha_of(d1, d2, z1, z2) : 0.0f;

    const float q0 = 1.0f - a0 + 1e-10f;  // lanes owning nothing: q = 1
    const float q1 = 1.0f - a1 + 1e-10f;

    // inclusive prefix product of per-lane products across the 32-lane group
    float scan = q0 * q1;
    #pragma unroll
    for (int off = 1; off < 32; off <<= 1) {
        const float t = __shfl_up(scan, off, 32);
        if (l >= off) scan *= t;
    }
    // exclusive
    float excl = __shfl_up(scan, 1, 32);
    if (l == 0) excl = 1.0f;

    const float T0 = excl;
    const float T1 = excl * q0;
    const float w0 = a0 * T0;
    const float w1 = a1 * T1;

    // per-ray scalar reductions (xor-reduce leaves the sum in all lanes)
    float wt   = w0 + w1;
    float dacc = w0 * 0.5f * (z0 + z1) + w1 * 0.5f * (z1 + z2);
    #pragma unroll
    for (int off = 1; off < 32; off <<= 1) {
        wt   += __shfl_xor(wt,   off, 32);
        dacc += __shfl_xor(dacc, off, 32);
    }

    // weights out
    float* __restrict__ w_out = out + OFF_W + (size_t)ray * SM1;
    if (l < 24) w_out[m0]     = w0;
    if (l < 23) w_out[m0 + 1] = w1;

    if (l == 0) {
        out[OFF_DEP + ray] = dacc / (wt + 0.001f);
        out[OFF_WT  + ray] = wt;
    }

    // ---- Phase 2: streaming color composite ------------------------------
    // composite_rgb = 2 * sum_m w_m * 0.5*(c_m + c_{m+1}) - 1
    //               = sum_m w_m * (c_m + c_{m+1}) - 1
    const float* __restrict__ colf = colors + (size_t)ray * S_SAMP * C_CH + l;

    float cp = colf[0];
    float ax = 0.0f;

    #pragma unroll
    for (int m = 0; m < SM1; ++m) {
        const float c  = colf[(size_t)(m + 1) * C_CH];
        const float wsrc = (m & 1) ? w1 : w0;
        const float wv = __shfl(wsrc, m >> 1, 32);   // compile-time src lane
        ax += wv * (c + cp);
        cp = c;
    }

    out[OFF_RGB + (size_t)ray * C_CH + l] = ax - 1.0f;
}

extern "C" void kernel_launch(void* const* d_in, const int* in_sizes, int n_in,
                              void* d_out, int out_size, void* d_ws, size_t ws_size,
                              hipStream_t stream) {
    const float* colors    = (const float*)d_in[0];
    const float* densities = (const float*)d_in[1];
    const float* depths    = (const float*)d_in[2];
    float* out = (float*)d_out;

    fused3_kernel<<<(NRAYS * 32) / 256, 256, 0, stream>>>(colors, densities, depths, out);
}

// Round 6
// 22.080 us; speedup vs baseline: 1.0058x; 1.0058x over previous
//
#include <hip/hip_runtime.h>
#include <math.h>

// Problem constants: B=4, R=4096, S=48, C=32
#define NRAYS   (4 * 4096)   // 16384
#define S_SAMP  48
#define C_CH    32
#define SM1     (S_SAMP - 1) // 47 midpoints

// Output flat layout (floats):
#define OFF_RGB   0
#define OFF_DEP   (NRAYS * C_CH)
#define OFF_W     (OFF_DEP + NRAYS)
#define OFF_WT    (OFF_W + NRAYS * SM1)

__device__ __forceinline__ float alpha_of(float da, float db, float za, float zb) {
    const float dmid = 0.5f * (da + db) - 1.0f;
    // fast stable softplus: max(x,0) + log(1 + exp(-|x|))
    const float e  = __expf(-fabsf(dmid));
    const float sp = fmaxf(dmid, 0.0f) + __logf(1.0f + e);
    return 1.0f - __expf(-sp * (zb - za));
}

// One 32-lane group per ray (2 rays per wave).
// Phase 1 (as round 5): lane l owns midpoints 2l,2l+1 (l<24); exclusive
//   transmittance via 5-step shfl_up prefix product over 32 lanes.
// Phase 2 (NEW): sample-split. Half-group h = l>>4 owns midpoints
//   24h..24h+23; lane li = l&15 owns channel pair li with float2 loads
//   (8 B/lane — round-4's coalescing sweet spot — at round-5's TLP).
//   Midpoint 47 is dead: its weight is lane23.w1 == 0; color load clamped.
__global__ __launch_bounds__(256) void fused4_kernel(
    const float* __restrict__ colors,     // [NRAYS, S, C]
    const float* __restrict__ densities,  // [NRAYS, S]
    const float* __restrict__ depths,     // [NRAYS, S]
    float* __restrict__ out)
{
    const int tid = blockIdx.x * 256 + threadIdx.x;
    const int ray = tid >> 5;
    const int l   = tid & 31;

    const float* __restrict__ den = densities + (size_t)ray * S_SAMP;
    const float* __restrict__ dep = depths    + (size_t)ray * S_SAMP;

    // ---- Phase 1: weights via lane-parallel scan -------------------------
    const int m0 = 2 * l;
    float d0 = 0.f, d1 = 0.f, d2 = 0.f, z0 = 0.f, z1 = 0.f, z2 = 0.f;
    if (l < 24) {
        d0 = den[m0];     z0 = dep[m0];
        d1 = den[m0 + 1]; z1 = dep[m0 + 1];
        if (l < 23) { d2 = den[m0 + 2]; z2 = dep[m0 + 2]; }
    }

    const float a0 = (l < 24) ? alpha_of(d0, d1, z0, z1) : 0.0f;
    const float a1 = (l < 23) ? alpha_of(d1, d2, z1, z2) : 0.0f;

    const float q0 = 1.0f - a0 + 1e-10f;   // non-owning lanes: q = 1
    const float q1 = 1.0f - a1 + 1e-10f;

    float scan = q0 * q1;
    #pragma unroll
    for (int off = 1; off < 32; off <<= 1) {
        const float t = __shfl_up(scan, off, 32);
        if (l >= off) scan *= t;
    }
    float excl = __shfl_up(scan, 1, 32);
    if (l == 0) excl = 1.0f;

    const float T0 = excl;
    const float T1 = excl * q0;
    const float w0 = a0 * T0;
    const float w1 = a1 * T1;              // lane>=23: 0

    float wt   = w0 + w1;
    float dacc = w0 * 0.5f * (z0 + z1) + w1 * 0.5f * (z1 + z2);
    #pragma unroll
    for (int off = 1; off < 32; off <<= 1) {
        wt   += __shfl_xor(wt,   off, 32);
        dacc += __shfl_xor(dacc, off, 32);
    }

    float* __restrict__ w_out = out + OFF_W + (size_t)ray * SM1;
    if (l < 24) w_out[m0]     = w0;
    if (l < 23) w_out[m0 + 1] = w1;

    if (l == 0) {
        out[OFF_DEP + ray] = dacc / (wt + 0.001f);
        out[OFF_WT  + ray] = wt;
    }

    // ---- Phase 2: streaming color composite, sample-split ----------------
    // composite_rgb = sum_m w_m * (c_m + c_{m+1}) - 1
    const int half  = l >> 4;          // 0: m=0..23, 1: m=24..46 (+dead 47)
    const int li    = l & 15;
    const int s0    = half * 24;
    const int lbase = 12 * half;       // weight-owner lane base for this half

    const float2* __restrict__ col2 =
        reinterpret_cast<const float2*>(colors) + (size_t)ray * S_SAMP * (C_CH / 2) + li;

    float2 cp = col2[(size_t)s0 * (C_CH / 2)];
    float ax = 0.0f, ay = 0.0f;

    #pragma unroll
    for (int mi = 0; mi < 24; ++mi) {
        // sample to load: s0+mi+1, clamped at 47 (only the dead m=47 hits it)
        const int sidx = (mi == 23) ? min(s0 + 24, S_SAMP - 1) : (s0 + mi + 1);
        const float2 c = col2[(size_t)sidx * (C_CH / 2)];
        // weight for midpoint m = s0+mi lives on lane 12*half + mi/2
        const float wsrc = (mi & 1) ? w1 : w0;
        const float wv = __shfl(wsrc, lbase + (mi >> 1), 32);
        ax += wv * (c.x + cp.x);
        ay += wv * (c.y + cp.y);
        cp = c;
    }

    // combine the two halves and write from half 0
    ax += __shfl_xor(ax, 16, 32);
    ay += __shfl_xor(ay, 16, 32);

    if (half == 0) {
        float2* __restrict__ rgb2 =
            reinterpret_cast<float2*>(out + OFF_RGB + (size_t)ray * C_CH) + li;
        *rgb2 = make_float2(ax - 1.0f, ay - 1.0f);
    }
}

extern "C" void kernel_launch(void* const* d_in, const int* in_sizes, int n_in,
                              void* d_out, int out_size, void* d_ws, size_t ws_size,
                              hipStream_t stream) {
    const float* colors    = (const float*)d_in[0];
    const float* densities = (const float*)d_in[1];
    const float* depths    = (const float*)d_in[2];
    float* out = (float*)d_out;

    fused4_kernel<<<(NRAYS * 32) / 256, 256, 0, stream>>>(colors, densities, depths, out);
}

// Round 7
// 21.432 us; speedup vs baseline: 1.0362x; 1.0302x over previous
//
#include <hip/hip_runtime.h>
#include <math.h>

// Problem constants: B=4, R=4096, S=48, C=32
#define NRAYS   (4 * 4096)   // 16384
#define S_SAMP  48
#define C_CH    32
#define SM1     (S_SAMP - 1) // 47 midpoints

// Output flat layout (floats):
#define OFF_RGB   0
#define OFF_DEP   (NRAYS * C_CH)
#define OFF_W     (OFF_DEP + NRAYS)
#define OFF_WT    (OFF_W + NRAYS * SM1)

__device__ __forceinline__ float alpha_of(float da, float db, float za, float zb) {
    const float dmid = 0.5f * (da + db) - 1.0f;
    // fast stable softplus: max(x,0) + log(1 + exp(-|x|))
    const float e  = __expf(-fabsf(dmid));
    const float sp = fmaxf(dmid, 0.0f) + __logf(1.0f + e);
    return 1.0f - __expf(-sp * (zb - za));
}

// One 16-lane group per ray (4 rays per wave).
// Phase 1 (round-4 structure): lane l owns midpoints 3l..3l+2 (lane 15 owns
//   45,46; its w2 == 0 stands in for the nonexistent w_47). Exclusive
//   transmittance via 4-step shfl_up prefix product.
// Phase 2 (per-SAMPLE composite): rgb = sum_s (w_{s-1}+w_s)*c_s - 1.
//   li = l&7 owns channel quad li (float4, 16 B/lane -> 8 lanes = 128 B row);
//   h = l>>3 owns samples 24h..24h+23. Exactly one float4 load per color
//   element, uniform 24-iter loop, 1 bpermute + 4 FMA per sample.
__global__ __launch_bounds__(256) void fused5_kernel(
    const float* __restrict__ colors,     // [NRAYS, S, C]
    const float* __restrict__ densities,  // [NRAYS, S]
    const float* __restrict__ depths,     // [NRAYS, S]
    float* __restrict__ out)
{
    const int tid = blockIdx.x * 256 + threadIdx.x;
    const int ray = tid >> 4;
    const int l   = tid & 15;

    const float* __restrict__ den = densities + (size_t)ray * S_SAMP;
    const float* __restrict__ dep = depths    + (size_t)ray * S_SAMP;

    // ---- Phase 1: weights via lane-parallel scan -------------------------
    const int m0 = 3 * l;
    const float d0 = den[m0], d1 = den[m0 + 1], d2 = den[m0 + 2];
    const float z0 = dep[m0], z1 = dep[m0 + 1], z2 = dep[m0 + 2];
    float d3 = 0.0f, z3 = 0.0f;
    if (l < 15) { d3 = den[m0 + 3]; z3 = dep[m0 + 3]; }

    const float a0 = alpha_of(d0, d1, z0, z1);
    const float a1 = alpha_of(d1, d2, z1, z2);
    const float a2 = (l < 15) ? alpha_of(d2, d3, z2, z3) : 0.0f;

    const float q0 = 1.0f - a0 + 1e-10f;
    const float q1 = 1.0f - a1 + 1e-10f;
    const float q2 = 1.0f - a2 + 1e-10f;

    float scan = q0 * q1 * q2;
    #pragma unroll
    for (int off = 1; off < 16; off <<= 1) {
        const float t = __shfl_up(scan, off, 16);
        if (l >= off) scan *= t;
    }
    float excl = __shfl_up(scan, 1, 16);
    if (l == 0) excl = 1.0f;

    const float T0 = excl;
    const float T1 = excl * q0;
    const float T2 = T1 * q1;
    const float w0 = a0 * T0;
    const float w1 = a1 * T1;
    const float w2 = a2 * T2;            // lane15: exactly 0 (= w_47)

    float wt   = w0 + w1 + w2;
    float dacc = w0 * 0.5f * (z0 + z1) + w1 * 0.5f * (z1 + z2) + w2 * 0.5f * (z2 + z3);
    #pragma unroll
    for (int off = 1; off < 16; off <<= 1) {
        wt   += __shfl_xor(wt,   off, 16);
        dacc += __shfl_xor(dacc, off, 16);
    }

    float* __restrict__ w_out = out + OFF_W + (size_t)ray * SM1;
    w_out[m0]     = w0;
    w_out[m0 + 1] = w1;
    if (l < 15) w_out[m0 + 2] = w2;

    if (l == 0) {
        out[OFF_DEP + ray] = dacc / (wt + 0.001f);
        out[OFF_WT  + ray] = wt;
    }

    // ---- Phase 2: per-sample composite with float4 loads ----------------
    // coeff_s = w_{s-1} + w_s   (w_{-1} = 0, w_47 = lane15.w2 = 0)
    // weight w_s lives on lane s/3, component s%3; for s = 24h+mi this is
    // lane 8h + mi/3, component mi%3 (compile-time under full unroll).
    const int h  = l >> 3;
    const int li = l & 7;
    const float4* __restrict__ col4 =
        reinterpret_cast<const float4*>(colors) + (size_t)ray * S_SAMP * (C_CH / 4) + li;

    const float w23 = __shfl(w2, 7, 16);       // weight of midpoint 23
    float prev = h ? w23 : 0.0f;               // w_{s0-1}

    float acc0 = 0.0f, acc1 = 0.0f, acc2 = 0.0f, acc3 = 0.0f;

    #pragma unroll
    for (int mi = 0; mi < 24; ++mi) {
        const int s = 24 * h + mi;             // per-lane sample index
        const float4 c = col4[(size_t)s * (C_CH / 4)];
        const float wsrc = (mi % 3 == 0) ? w0 : ((mi % 3 == 1) ? w1 : w2);
        const float ws   = __shfl(wsrc, 8 * h + mi / 3, 16);
        const float coeff = prev + ws;
        acc0 += coeff * c.x;
        acc1 += coeff * c.y;
        acc2 += coeff * c.z;
        acc3 += coeff * c.w;
        prev = ws;
    }

    // combine the two halves (lane l with lane l^8 share channel quad li)
    acc0 += __shfl_xor(acc0, 8, 16);
    acc1 += __shfl_xor(acc1, 8, 16);
    acc2 += __shfl_xor(acc2, 8, 16);
    acc3 += __shfl_xor(acc3, 8, 16);

    if (h == 0) {
        float4* __restrict__ rgb4 =
            reinterpret_cast<float4*>(out + OFF_RGB + (size_t)ray * C_CH) + li;
        *rgb4 = make_float4(acc0 - 1.0f, acc1 - 1.0f, acc2 - 1.0f, acc3 - 1.0f);
    }
}

extern "C" void kernel_launch(void* const* d_in, const int* in_sizes, int n_in,
                              void* d_out, int out_size, void* d_ws, size_t ws_size,
                              hipStream_t stream) {
    const float* colors    = (const float*)d_in[0];
    const float* densities = (const float*)d_in[1];
    const float* depths    = (const float*)d_in[2];
    float* out = (float*)d_out;

    fused5_kernel<<<(NRAYS * 16) / 256, 256, 0, stream>>>(colors, densities, depths, out);
}